// Round 4
// baseline (178.319 us; speedup 1.0000x reference)
//
#include <hip/hip_runtime.h>
#include <hip/hip_bf16.h>

#define NROWS 65536
#define DIM   256
#define KC    512
#define ALPHA 0.05f

typedef __attribute__((ext_vector_type(8))) short bf16x8;
typedef __attribute__((ext_vector_type(4))) float f32x4;

typedef const __attribute__((address_space(1))) unsigned int GU32;
typedef __attribute__((address_space(3))) unsigned int LU32;

static __device__ __forceinline__ void gl_lds16(const void* g, void* l) {
    __builtin_amdgcn_global_load_lds((GU32*)g, (LU32*)l, 16, 0, 0);
}

static __device__ __forceinline__ unsigned short f2bf(float f) {
    union { __hip_bfloat16 h; unsigned short u; } c;
    c.h = __float2bfloat16(f);
    return c.u;
}

// Fragment-major center layout (verified R1-R3):
// uint4 index = (t16*8 + kk)*64 + l, t16 = center>>4, l = q*16+m holds
// center row t16*16+m, elems kk*32+q*8 .. +7. Chunk c = t16 {2c,2c+1} =
// 1024 consecutive uint4 = 16 KB contiguous.
__global__ void prep_centers(const float* __restrict__ centers,
                             float* __restrict__ csqh,
                             uint4* __restrict__ cbf2,
                             float* __restrict__ out) {
    const int t = threadIdx.x;
    const int r = blockIdx.x * 8 + (t >> 5);  // center row
    const int e = t & 31;                     // 8-elem group within row
    const float4* cv = reinterpret_cast<const float4*>(centers);
    float4 v0 = cv[r * 64 + e * 2];
    float4 v1 = cv[r * 64 + e * 2 + 1];
    float s = v0.x * v0.x + v0.y * v0.y + v0.z * v0.z + v0.w * v0.w
            + v1.x * v1.x + v1.y * v1.y + v1.z * v1.z + v1.w * v1.w;
    unsigned short o[8];
    o[0] = f2bf(v0.x); o[1] = f2bf(v0.y); o[2] = f2bf(v0.z); o[3] = f2bf(v0.w);
    o[4] = f2bf(v1.x); o[5] = f2bf(v1.y); o[6] = f2bf(v1.z); o[7] = f2bf(v1.w);
    const int t16 = r >> 4, m = r & 15;
    const int kk = e >> 2, q = e & 3, l = q * 16 + m;
    cbf2[(t16 * 8 + kk) * 64 + l] = *reinterpret_cast<uint4*>(o);
    #pragma unroll
    for (int off = 16; off; off >>= 1) s += __shfl_xor(s, off, 64);
    if (e == 0) csqh[r] = 0.5f * s;
    if (blockIdx.x == 0 && t == 0) out[0] = 0.f;
}

// Block: 64 rows, 256 thr. Wave w: row-group g=w>>1 (32 rows, afr resident),
// col-half h=w&1 (16 cols per chunk). B double-buffered in LDS via
// global_load_lds(16B); 16 chunks of 32 centers; one barrier per chunk.
__global__ __launch_bounds__(256, 4) void kmeans_main(
    const float* __restrict__ emb,
    const uint4* __restrict__ cbf2,
    const float* __restrict__ csqh_g,
    float* __restrict__ out) {
    __shared__ uint4 sB[2][1024];      // 2 x 16 KB double buffer
    __shared__ float csq_s[KC];        // 2 KB
    __shared__ float xsq_s[64];
    __shared__ float rowmax_s[2][64];

    const int t = threadIdx.x;
    const int w = t >> 6;
    const int lane = t & 63;
    const int m = lane & 15;
    const int q = lane >> 4;
    const int g = w >> 1;      // row-group 0/1
    const int h = w & 1;       // col-half within chunk
    const int r0 = blockIdx.x * 64 + g * 32;

    // ---- prefetch chunk 0 into sB[0] (async, direct-to-LDS) ----
    {
        const char* gb = (const char*)cbf2;          // chunk 0 base
        char* lb = (char*)(&sB[0][0]);
        #pragma unroll
        for (int j = 0; j < 4; ++j)
            gl_lds16(gb + (j * 256 + t) * 16, lb + (j * 256 + t) * 16);
    }
    // ---- stage c_sq/2 to LDS ----
    csq_s[t] = csqh_g[t];
    csq_s[t + 256] = csqh_g[t + 256];

    // ---- A fragments: fp32 global -> bf16 regs; exact fp32 xsq en route ----
    bf16x8 afr[2][8];
    float xp[2];
    #pragma unroll
    for (int rt = 0; rt < 2; ++rt) {
        float s = 0.f;
        const float* rowp = emb + (size_t)(r0 + rt * 16 + m) * DIM;
        #pragma unroll
        for (int kk = 0; kk < 8; ++kk) {
            const float4* p = reinterpret_cast<const float4*>(rowp + kk * 32 + q * 8);
            float4 v0 = p[0], v1 = p[1];
            s += v0.x * v0.x + v0.y * v0.y + v0.z * v0.z + v0.w * v0.w
               + v1.x * v1.x + v1.y * v1.y + v1.z * v1.z + v1.w * v1.w;
            bf16x8 a;
            a[0] = (short)f2bf(v0.x); a[1] = (short)f2bf(v0.y);
            a[2] = (short)f2bf(v0.z); a[3] = (short)f2bf(v0.w);
            a[4] = (short)f2bf(v1.x); a[5] = (short)f2bf(v1.y);
            a[6] = (short)f2bf(v1.z); a[7] = (short)f2bf(v1.w);
            afr[rt][kk] = a;
        }
        xp[rt] = s;
    }
    #pragma unroll
    for (int rt = 0; rt < 2; ++rt) {
        xp[rt] += __shfl_xor(xp[rt], 16, 64);
        xp[rt] += __shfl_xor(xp[rt], 32, 64);
        if (h == 0 && q == 0) xsq_s[g * 32 + rt * 16 + m] = xp[rt];
    }
    __syncthreads();   // publishes chunk 0, csq, xsq

    float maxv[2][4];
    #pragma unroll
    for (int rt = 0; rt < 2; ++rt)
        #pragma unroll
        for (int rg = 0; rg < 4; ++rg) maxv[rt][rg] = -1e30f;

    // ---- K-loop: 16 chunks of 32 centers, double-buffered LDS ----
    for (int c = 0; c < 16; ++c) {
        if (c < 15) {  // prefetch next chunk into the other buffer
            const char* gb = (const char*)(cbf2 + (c + 1) * 1024);
            char* lb = (char*)(&sB[(c + 1) & 1][0]);
            #pragma unroll
            for (int j = 0; j < 4; ++j)
                gl_lds16(gb + (j * 256 + t) * 16, lb + (j * 256 + t) * 16);
        }
        // this wave's col-tile: center t16 = 2c+h, col = (2c+h)*16 + m
        const float ci = -csq_s[(2 * c + h) * 16 + m];
        const char* bb = (const char*)(&sB[c & 1][0]) + h * 8192 + lane * 16;

        f32x4 acc0 = {ci, ci, ci, ci};
        f32x4 acc1 = {ci, ci, ci, ci};
        bf16x8 bf0[4];
        #pragma unroll
        for (int kk = 0; kk < 4; ++kk)
            bf0[kk] = *reinterpret_cast<const bf16x8*>(bb + kk * 1024);
        #pragma unroll
        for (int kk = 0; kk < 4; ++kk) {
            acc0 = __builtin_amdgcn_mfma_f32_16x16x32_bf16(afr[0][kk], bf0[kk], acc0, 0, 0, 0);
            acc1 = __builtin_amdgcn_mfma_f32_16x16x32_bf16(afr[1][kk], bf0[kk], acc1, 0, 0, 0);
        }
        #pragma unroll
        for (int kk = 0; kk < 4; ++kk)
            bf0[kk] = *reinterpret_cast<const bf16x8*>(bb + (kk + 4) * 1024);
        #pragma unroll
        for (int kk = 0; kk < 4; ++kk) {
            acc0 = __builtin_amdgcn_mfma_f32_16x16x32_bf16(afr[0][kk + 4], bf0[kk], acc0, 0, 0, 0);
            acc1 = __builtin_amdgcn_mfma_f32_16x16x32_bf16(afr[1][kk + 4], bf0[kk], acc1, 0, 0, 0);
        }
        #pragma unroll
        for (int rg = 0; rg < 4; ++rg) {
            maxv[0][rg] = fmaxf(maxv[0][rg], acc0[rg]);
            maxv[1][rg] = fmaxf(maxv[1][rg], acc1[rg]);
        }
        __syncthreads();  // all waves done with buf[c&1]; drains prefetch
    }

    // ---- per-row max over this wave's cols (xor over m-lanes) ----
    #pragma unroll
    for (int rt = 0; rt < 2; ++rt)
        #pragma unroll
        for (int rg = 0; rg < 4; ++rg) {
            float v = maxv[rt][rg];
            v = fmaxf(v, __shfl_xor(v, 1, 64));
            v = fmaxf(v, __shfl_xor(v, 2, 64));
            v = fmaxf(v, __shfl_xor(v, 4, 64));
            v = fmaxf(v, __shfl_xor(v, 8, 64));
            // C/D layout: row = rt*16 + q*4 + rg (col = m)  [m89/m91]
            if (m == 0) rowmax_s[h][g * 32 + rt * 16 + q * 4 + rg] = v;
        }
    __syncthreads();

    // ---- combine halves, d = sqrt(x^2 - 2*max(cross - c^2/2)), sum ----
    if (t < 64) {
        float M = fmaxf(rowmax_s[0][t], rowmax_s[1][t]);
        float d = sqrtf(fmaxf(xsq_s[t] - 2.f * M, 0.f));
        #pragma unroll
        for (int off = 1; off < 64; off <<= 1) d += __shfl_xor(d, off, 64);
        if (t == 0) atomicAdd(out, d * (ALPHA / (float)NROWS));
    }
}

extern "C" void kernel_launch(void* const* d_in, const int* in_sizes, int n_in,
                              void* d_out, int out_size, void* d_ws, size_t ws_size,
                              hipStream_t stream) {
    const float* emb     = (const float*)d_in[0];   // [65536, 256] fp32
    const float* centers = (const float*)d_in[1];   // [512, 256] fp32
    float* out = (float*)d_out;

    float* csqh = (float*)d_ws;                       // 512 * 4 B (= ||c||^2/2)
    uint4* cbf2 = (uint4*)((char*)d_ws + 2048);       // 256 KB fragment-major bf16

    prep_centers<<<dim3(KC / 8), dim3(256), 0, stream>>>(centers, csqh, cbf2, out);
    kmeans_main<<<dim3(NROWS / 64), dim3(256), 0, stream>>>(emb, cbf2, csqh, out);
}

// Round 5
// 125.307 us; speedup vs baseline: 1.4231x; 1.4231x over previous
//
#include <hip/hip_runtime.h>
#include <hip/hip_bf16.h>

#define NROWS 65536
#define DIM   256
#define KC    512
#define ALPHA 0.05f

typedef __attribute__((ext_vector_type(8))) short bf16x8;
typedef __attribute__((ext_vector_type(4))) float f32x4;

typedef const __attribute__((address_space(1))) unsigned int GU32;
typedef __attribute__((address_space(3))) unsigned int LU32;

static __device__ __forceinline__ void gl_lds16(const void* g, void* l) {
    __builtin_amdgcn_global_load_lds((GU32*)g, (LU32*)l, 16, 0, 0);
}

static __device__ __forceinline__ unsigned short f2bf(float f) {
    union { __hip_bfloat16 h; unsigned short u; } c;
    c.h = __float2bfloat16(f);
    return c.u;
}

// Fragment-major center layout (verified R1-R4):
// uint4 index = (t16*8 + kk)*64 + l, t16 = center>>4, l = q*16+m holds
// center row t16*16+m, elems kk*32+q*8 .. +7. Chunk c = t16 {2c,2c+1} =
// 1024 consecutive uint4 = 16 KB contiguous.
__global__ void prep_centers(const float* __restrict__ centers,
                             float* __restrict__ csqh,
                             uint4* __restrict__ cbf2,
                             float* __restrict__ out) {
    const int t = threadIdx.x;
    const int r = blockIdx.x * 8 + (t >> 5);  // center row
    const int e = t & 31;                     // 8-elem group within row
    const float4* cv = reinterpret_cast<const float4*>(centers);
    float4 v0 = cv[r * 64 + e * 2];
    float4 v1 = cv[r * 64 + e * 2 + 1];
    float s = v0.x * v0.x + v0.y * v0.y + v0.z * v0.z + v0.w * v0.w
            + v1.x * v1.x + v1.y * v1.y + v1.z * v1.z + v1.w * v1.w;
    unsigned short o[8];
    o[0] = f2bf(v0.x); o[1] = f2bf(v0.y); o[2] = f2bf(v0.z); o[3] = f2bf(v0.w);
    o[4] = f2bf(v1.x); o[5] = f2bf(v1.y); o[6] = f2bf(v1.z); o[7] = f2bf(v1.w);
    const int t16 = r >> 4, m = r & 15;
    const int kk = e >> 2, q = e & 3, l = q * 16 + m;
    cbf2[(t16 * 8 + kk) * 64 + l] = *reinterpret_cast<uint4*>(o);
    #pragma unroll
    for (int off = 16; off; off >>= 1) s += __shfl_xor(s, off, 64);
    if (e == 0) csqh[r] = 0.5f * s;
    if (blockIdx.x == 0 && t == 0) out[0] = 0.f;
}

// Block: 64 rows, 256 thr. Wave w: row-group g=w>>1 (32 rows, afr resident,
// 64 VGPRs), col-half h=w&1 (16 cols per chunk). B double-buffered in LDS via
// global_load_lds(16B), shared by all 4 waves (L2 B-traffic once per block).
// __launch_bounds__(256,3): 170-reg unified budget -> afr stays in registers
// (the (256,4)/128-reg cap was what forced the R3/R4 scratch spill).
__global__ __launch_bounds__(256, 3) void kmeans_main(
    const float* __restrict__ emb,
    const uint4* __restrict__ cbf2,
    const float* __restrict__ csqh_g,
    float* __restrict__ out) {
    __shared__ uint4 sB[2][1024];      // 2 x 16 KB double buffer
    __shared__ float csq_s[KC];        // 2 KB
    __shared__ float xsq_s[64];
    __shared__ float rowmax_s[2][64];

    const int t = threadIdx.x;
    const int w = t >> 6;
    const int lane = t & 63;
    const int m = lane & 15;
    const int q = lane >> 4;
    const int g = w >> 1;      // row-group 0/1
    const int h = w & 1;       // col-half within chunk
    const int r0 = blockIdx.x * 64 + g * 32;

    // ---- prefetch chunk 0 into sB[0] (async, direct-to-LDS) ----
    {
        const char* gb = (const char*)cbf2;          // chunk 0 base
        char* lb = (char*)(&sB[0][0]);
        #pragma unroll
        for (int j = 0; j < 4; ++j)
            gl_lds16(gb + (j * 256 + t) * 16, lb + (j * 256 + t) * 16);
    }
    // ---- stage c_sq/2 to LDS ----
    csq_s[t] = csqh_g[t];
    csq_s[t + 256] = csqh_g[t + 256];

    // ---- A fragments: fp32 global -> bf16 regs; exact fp32 xsq en route ----
    bf16x8 afr[2][8];
    float xp[2];
    #pragma unroll
    for (int rt = 0; rt < 2; ++rt) {
        float s = 0.f;
        const float* rowp = emb + (size_t)(r0 + rt * 16 + m) * DIM;
        #pragma unroll
        for (int kk = 0; kk < 8; ++kk) {
            const float4* p = reinterpret_cast<const float4*>(rowp + kk * 32 + q * 8);
            float4 v0 = p[0], v1 = p[1];
            s += v0.x * v0.x + v0.y * v0.y + v0.z * v0.z + v0.w * v0.w
               + v1.x * v1.x + v1.y * v1.y + v1.z * v1.z + v1.w * v1.w;
            bf16x8 a;
            a[0] = (short)f2bf(v0.x); a[1] = (short)f2bf(v0.y);
            a[2] = (short)f2bf(v0.z); a[3] = (short)f2bf(v0.w);
            a[4] = (short)f2bf(v1.x); a[5] = (short)f2bf(v1.y);
            a[6] = (short)f2bf(v1.z); a[7] = (short)f2bf(v1.w);
            afr[rt][kk] = a;
        }
        xp[rt] = s;
    }
    #pragma unroll
    for (int rt = 0; rt < 2; ++rt) {
        xp[rt] += __shfl_xor(xp[rt], 16, 64);
        xp[rt] += __shfl_xor(xp[rt], 32, 64);
        if (h == 0 && q == 0) xsq_s[g * 32 + rt * 16 + m] = xp[rt];
    }
    __syncthreads();   // publishes chunk 0, csq, xsq

    float maxv[2][4];
    #pragma unroll
    for (int rt = 0; rt < 2; ++rt)
        #pragma unroll
        for (int rg = 0; rg < 4; ++rg) maxv[rt][rg] = -1e30f;

    // ---- K-loop: 16 chunks of 32 centers, double-buffered LDS ----
    for (int c = 0; c < 16; ++c) {
        if (c < 15) {  // prefetch next chunk into the other buffer
            const char* gb = (const char*)(cbf2 + (c + 1) * 1024);
            char* lb = (char*)(&sB[(c + 1) & 1][0]);
            #pragma unroll
            for (int j = 0; j < 4; ++j)
                gl_lds16(gb + (j * 256 + t) * 16, lb + (j * 256 + t) * 16);
        }
        // this wave's col-tile: center t16 = 2c+h, col = (2c+h)*16 + m
        const float ci = -csq_s[(2 * c + h) * 16 + m];
        const char* bb = (const char*)(&sB[c & 1][0]) + h * 8192 + lane * 16;

        f32x4 acc0 = {ci, ci, ci, ci};
        f32x4 acc1 = {ci, ci, ci, ci};
        bf16x8 bf0[4];
        #pragma unroll
        for (int kk = 0; kk < 4; ++kk)
            bf0[kk] = *reinterpret_cast<const bf16x8*>(bb + kk * 1024);
        #pragma unroll
        for (int kk = 0; kk < 4; ++kk) {
            acc0 = __builtin_amdgcn_mfma_f32_16x16x32_bf16(afr[0][kk], bf0[kk], acc0, 0, 0, 0);
            acc1 = __builtin_amdgcn_mfma_f32_16x16x32_bf16(afr[1][kk], bf0[kk], acc1, 0, 0, 0);
        }
        #pragma unroll
        for (int kk = 0; kk < 4; ++kk)
            bf0[kk] = *reinterpret_cast<const bf16x8*>(bb + (kk + 4) * 1024);
        #pragma unroll
        for (int kk = 0; kk < 4; ++kk) {
            acc0 = __builtin_amdgcn_mfma_f32_16x16x32_bf16(afr[0][kk + 4], bf0[kk], acc0, 0, 0, 0);
            acc1 = __builtin_amdgcn_mfma_f32_16x16x32_bf16(afr[1][kk + 4], bf0[kk], acc1, 0, 0, 0);
        }
        #pragma unroll
        for (int rg = 0; rg < 4; ++rg) {
            maxv[0][rg] = fmaxf(maxv[0][rg], acc0[rg]);
            maxv[1][rg] = fmaxf(maxv[1][rg], acc1[rg]);
        }
        __syncthreads();  // all waves done with buf[c&1]; drains prefetch
    }

    // ---- per-row max over this wave's cols (xor over m-lanes) ----
    #pragma unroll
    for (int rt = 0; rt < 2; ++rt)
        #pragma unroll
        for (int rg = 0; rg < 4; ++rg) {
            float v = maxv[rt][rg];
            v = fmaxf(v, __shfl_xor(v, 1, 64));
            v = fmaxf(v, __shfl_xor(v, 2, 64));
            v = fmaxf(v, __shfl_xor(v, 4, 64));
            v = fmaxf(v, __shfl_xor(v, 8, 64));
            // C/D layout: row = rt*16 + q*4 + rg (col = m)  [m89/m91]
            if (m == 0) rowmax_s[h][g * 32 + rt * 16 + q * 4 + rg] = v;
        }
    __syncthreads();

    // ---- combine halves, d = sqrt(x^2 - 2*max(cross - c^2/2)), sum ----
    if (t < 64) {
        float M = fmaxf(rowmax_s[0][t], rowmax_s[1][t]);
        float d = sqrtf(fmaxf(xsq_s[t] - 2.f * M, 0.f));
        #pragma unroll
        for (int off = 1; off < 64; off <<= 1) d += __shfl_xor(d, off, 64);
        if (t == 0) atomicAdd(out, d * (ALPHA / (float)NROWS));
    }
}

extern "C" void kernel_launch(void* const* d_in, const int* in_sizes, int n_in,
                              void* d_out, int out_size, void* d_ws, size_t ws_size,
                              hipStream_t stream) {
    const float* emb     = (const float*)d_in[0];   // [65536, 256] fp32
    const float* centers = (const float*)d_in[1];   // [512, 256] fp32
    float* out = (float*)d_out;

    float* csqh = (float*)d_ws;                       // 512 * 4 B (= ||c||^2/2)
    uint4* cbf2 = (uint4*)((char*)d_ws + 2048);       // 256 KB fragment-major bf16

    prep_centers<<<dim3(KC / 8), dim3(256), 0, stream>>>(centers, csqh, cbf2, out);
    kmeans_main<<<dim3(NROWS / 64), dim3(256), 0, stream>>>(emb, cbf2, csqh, out);
}